// Round 12
// baseline (153.348 us; speedup 1.0000x reference)
//
#include <hip/hip_runtime.h>
#include <hip/hip_bf16.h>
#include <hip/hip_fp16.h>

// Fully fused QuanvolutionHybridClassifier forward (round 11 design,
// resubmitted — round-11 bench failed on GPU acquisition, no counters).
//
// Circuit collapse (verified): with a_w = d_w + q_w,
//   z0 = cos a0
//   z1 = cos q4 * cos a0 * cos a1 - sin q4 * sin a1
//   z2 = z1 * cos a2
//   z3 = cos a2 * cos a3
//
// Round-11: round-10 structure (best measured, kernel ~31us) with ONE
// lever: comb stored as fp16 -> LDS 25.4KB -> 12.9KB per block, and
// __launch_bounds__(256,8): 8 blocks/CU so the whole 2048-block grid is
// co-resident (kills the 6+2 straggler round, 33% idle span) and TLP
// rises 24->32 waves/CU. fp16 (not bf16): 2^-11 rel err keeps added
// logit error <0.001. Step-3 shape / packed 35-shuffle reduce unchanged.

#define SPB 4          // samples per block
#define THREADS 256
#define NCLS 10
#define FEAT 1568      // 784 flat + 784 quantum

__global__ __launch_bounds__(THREADS, 8)
void quanv_fused_kernel(const float* __restrict__ x,        // [B,1,28,28]
                        const float* __restrict__ conv_w,   // [4,1,2,2]
                        const float* __restrict__ conv_b,   // [4]
                        const float* __restrict__ q_params, // [5]
                        const float* __restrict__ lin_w,    // [10,1568]
                        const float* __restrict__ lin_b,    // [10]
                        float* __restrict__ out)            // [B,10]
{
    __shared__ __attribute__((aligned(16))) __half comb[SPB][FEAT]; // 12544 B
    __shared__ float part[SPB][2][12];   // [sample][K-half][class(+pad)]

    const int tid = threadIdx.x;
    const int n0  = blockIdx.x * SPB;

    // ---- uniform small params (L1-broadcast loads) ----
    float W[4][4], Bc[4];
    #pragma unroll
    for (int c = 0; c < 4; ++c) {
        #pragma unroll
        for (int k = 0; k < 4; ++k) W[c][k] = conv_w[c * 4 + k];
        Bc[c] = conv_b[c];
    }
    const float qp0 = q_params[0], qp1 = q_params[1];
    const float qp2 = q_params[2], qp3 = q_params[3];
    const float q4  = q_params[4];
    const float cq4 = __cosf(q4), sq4 = __sinf(q4);

    // ---- Step 1: conv (2x2, stride 2, 4 ch) -> flat region comb[s][0..783]
    // fp32 math, fp16 store (pairs, r even -> 4B aligned).
    for (int p = tid; p < SPB * 14 * 7; p += THREADS) {
        const int s = p / 98, t = p % 98;
        const int h = t / 7, wp = t % 7;
        const float* xp = x + (size_t)(n0 + s) * 784 + 56 * h + 4 * wp;
        const float4 r0 = *reinterpret_cast<const float4*>(xp);
        const float4 r1 = *reinterpret_cast<const float4*>(xp + 28);
        const int r = h * 14 + 2 * wp;
        #pragma unroll
        for (int c = 0; c < 4; ++c) {
            const float v0 =
                fmaf(r0.x, W[c][0], fmaf(r0.y, W[c][1],
                fmaf(r1.x, W[c][2], fmaf(r1.y, W[c][3], Bc[c]))));
            const float v1 =
                fmaf(r0.z, W[c][0], fmaf(r0.w, W[c][1],
                fmaf(r1.z, W[c][2], fmaf(r1.w, W[c][3], Bc[c]))));
            *reinterpret_cast<__half2*>(&comb[s][c * 196 + r]) =
                __floats2half2_rn(v0, v1);
        }
    }
    __syncthreads();

    // ---- Step 2: quantum features on 2x2 patches of the 28x28 view of flat
    for (int p = tid; p < SPB * 196; p += THREADS) {
        const int s = p / 196, r = p % 196;
        const int i = r / 14, j = r % 14;
        const int base = 56 * i + 2 * j;   // even -> 4B aligned
        const float2 d01 = __half22float2(
            *reinterpret_cast<const __half2*>(&comb[s][base]));
        const float2 d23 = __half22float2(
            *reinterpret_cast<const __half2*>(&comb[s][base + 28]));
        const float a0 = d01.x + qp0, a1 = d01.y + qp1;
        const float a2 = d23.x + qp2, a3 = d23.y + qp3;
        const float c0 = __cosf(a0);
        const float c1 = __cosf(a1), s1 = __sinf(a1);
        const float c2 = __cosf(a2), c3 = __cosf(a3);
        const float z0 = c0;
        const float z1 = cq4 * c0 * c1 - sq4 * s1;
        const float z2 = z1 * c2;
        const float z3 = c2 * c3;
        union { uint2 u; __half2 h[2]; } O;
        O.h[0] = __floats2half2_rn(z0, z1);
        O.h[1] = __floats2half2_rn(z2, z3);
        *reinterpret_cast<uint2*>(&comb[s][784 + r * 4]) = O.u;  // 8B aligned
    }
    __syncthreads();

    // ---- Step 3: linear [1568]x[10] + log_softmax.
    // Wave w = (pair p, K-half h): samples {2p, 2p+1}, K in [784h, 784h+784).
    const int wave = tid >> 6, lane = tid & 63;
    const int pr = wave & 1;
    const int h  = wave >> 1;
    const int s0 = 2 * pr, s1 = s0 + 1;
    const int kbase = h * 784;

    float acc0[NCLS], acc1[NCLS];
    #pragma unroll
    for (int c = 0; c < NCLS; ++c) { acc0[c] = 0.f; acc1[c] = 0.f; }

    // 3 full strips of 256 floats: covers [kbase, kbase+768)
    #pragma unroll
    for (int kb = 0; kb < 3; ++kb) {
        const int k = kbase + kb * 256 + lane * 4;   // 8B-aligned fp16 quad
        union { uint2 u; __half2 hh[2]; } U0, U1;
        U0.u = *reinterpret_cast<const uint2*>(&comb[s0][k]);
        U1.u = *reinterpret_cast<const uint2*>(&comb[s1][k]);
        const float2 a0 = __half22float2(U0.hh[0]);
        const float2 b0 = __half22float2(U0.hh[1]);
        const float2 a1 = __half22float2(U1.hh[0]);
        const float2 b1 = __half22float2(U1.hh[1]);
        const float4 v0 = make_float4(a0.x, a0.y, b0.x, b0.y);
        const float4 v1 = make_float4(a1.x, a1.y, b1.x, b1.y);
        #pragma unroll
        for (int c = 0; c < NCLS; ++c) {
            const float4 w4 = *reinterpret_cast<const float4*>(&lin_w[c * FEAT + k]);
            acc0[c] = fmaf(v0.x, w4.x, fmaf(v0.y, w4.y,
                      fmaf(v0.z, w4.z, fmaf(v0.w, w4.w, acc0[c]))));
            acc1[c] = fmaf(v1.x, w4.x, fmaf(v1.y, w4.y,
                      fmaf(v1.z, w4.z, fmaf(v1.w, w4.w, acc1[c]))));
        }
    }
    // tail [kbase+768, kbase+784): 16 scalars, lanes 0..15
    if (lane < 16) {
        const int k = kbase + 768 + lane;
        const float v0 = __half2float(comb[s0][k]);
        const float v1 = __half2float(comb[s1][k]);
        #pragma unroll
        for (int c = 0; c < NCLS; ++c) {
            const float w = lin_w[c * FEAT + k];
            acc0[c] = fmaf(v0, w, acc0[c]);
            acc1[c] = fmaf(v1, w, acc1[c]);
        }
    }

    // ---- Packed multi-value wave reduction: 20 partials -> 5 per lane.
    float w10[10];
    {
        const bool hi = (lane & 1) != 0;
        #pragma unroll
        for (int i = 0; i < 10; ++i) {
            const float t = hi ? acc0[i] : acc1[i];        // given-away half
            const float r = __shfl_xor(t, 1, 64);
            w10[i] = (hi ? acc1[i] : acc0[i]) + r;
        }
    }
    float w5[5];
    {
        const bool hi2 = (lane & 2) != 0;
        #pragma unroll
        for (int i = 0; i < 5; ++i) {
            const float t = hi2 ? w10[i] : w10[5 + i];
            const float r = __shfl_xor(t, 2, 64);
            w5[i] = (hi2 ? w10[5 + i] : w10[i]) + r;
        }
    }
    #pragma unroll
    for (int m = 4; m < 64; m <<= 1) {
        #pragma unroll
        for (int i = 0; i < 5; ++i)
            w5[i] += __shfl_xor(w5[i], m, 64);
    }
    // Lane q = lane&3: q0: acc0[0..4]  q1: acc1[0..4]  q2: acc0[5..9]  q3: acc1[5..9]
    if (lane < 4) {
        const int ss  = (lane & 1) ? s1 : s0;
        const int co  = (lane & 2) ? 5 : 0;
        #pragma unroll
        for (int i = 0; i < 5; ++i)
            part[ss][h][co + i] = w5[i];
    }
    __syncthreads();

    // ---- Epilogue: one thread per sample combines K-halves + log_softmax
    if (tid < SPB) {
        const int s = tid;
        float lg[NCLS], mx = -1e30f;
        #pragma unroll
        for (int c = 0; c < NCLS; ++c) {
            lg[c] = part[s][0][c] + part[s][1][c] + lin_b[c];
            mx = fmaxf(mx, lg[c]);
        }
        float sum = 0.f;
        #pragma unroll
        for (int c = 0; c < NCLS; ++c) sum += __expf(lg[c] - mx);
        const float lse = mx + __logf(sum);
        float* o = out + (size_t)(n0 + s) * NCLS;
        #pragma unroll
        for (int c = 0; c < NCLS; ++c) o[c] = lg[c] - lse;
    }
}

extern "C" void kernel_launch(void* const* d_in, const int* in_sizes, int n_in,
                              void* d_out, int out_size, void* d_ws, size_t ws_size,
                              hipStream_t stream) {
    const float* x        = (const float*)d_in[0];
    const float* conv_w   = (const float*)d_in[1];
    const float* conv_b   = (const float*)d_in[2];
    const float* q_params = (const float*)d_in[3];
    const float* lin_w    = (const float*)d_in[4];
    const float* lin_b    = (const float*)d_in[5];
    float* out = (float*)d_out;

    const int B = in_sizes[0] / 784;   // 8192
    const int nblocks = B / SPB;       // 2048

    quanv_fused_kernel<<<nblocks, THREADS, 0, stream>>>(
        x, conv_w, conv_b, q_params, lin_w, lin_b, out);
}

// Round 14
// 93.487 us; speedup vs baseline: 1.6403x; 1.6403x over previous
//
#include <hip/hip_runtime.h>
#include <hip/hip_bf16.h>
#include <hip/hip_fp16.h>

// Fully fused QuanvolutionHybridClassifier forward (round 13 design,
// resubmitted — round-13 bench failed on GPU acquisition, no counters).
//
// Circuit collapse (verified): with a_w = d_w + q_w,
//   z0 = cos a0
//   z1 = cos q4 * cos a0 * cos a1 - sin q4 * sin a1
//   z2 = z1 * cos a2
//   z3 = cos a2 * cos a3
//
// Round-13: r12 showed __launch_bounds__(256,8) + 20 accumulators =>
// VGPR cap 64 -> compiler spilled (VGPR_Count 32, 290MB scratch traffic,
// 89us). Occupancy lever worked (65%); spill killed it. Fix: CLASS-split
// waves instead of K-split: wave = (pair, class-group) = 2 samples x 5
// classes x full K -> 10 accumulators (~40 live VGPR, fits 64 cap).
// lin_w sharing preserved (2 samples per w4 load, same bytes as r10).
// fp16 comb (r12 measured absmax 0.03125 = PASS) -> 13KB LDS -> 8
// blocks/CU, 2048-block grid fully resident, 32 waves/CU.
// Reduction: 10 -> 5 pack (xor1) + 5-stage butterfly = 30 shuffles.

#define SPB 4          // samples per block
#define THREADS 256
#define NCLS 10
#define FEAT 1568      // 784 flat + 784 quantum

__global__ __launch_bounds__(THREADS, 8)
void quanv_fused_kernel(const float* __restrict__ x,        // [B,1,28,28]
                        const float* __restrict__ conv_w,   // [4,1,2,2]
                        const float* __restrict__ conv_b,   // [4]
                        const float* __restrict__ q_params, // [5]
                        const float* __restrict__ lin_w,    // [10,1568]
                        const float* __restrict__ lin_b,    // [10]
                        float* __restrict__ out)            // [B,10]
{
    __shared__ __attribute__((aligned(16))) __half comb[SPB][FEAT]; // 12544 B
    __shared__ float part[SPB][2][8];    // [sample][class-group][class-in-group]

    const int tid = threadIdx.x;
    const int n0  = blockIdx.x * SPB;

    // ---- uniform small params (L1-broadcast loads) ----
    float W[4][4], Bc[4];
    #pragma unroll
    for (int c = 0; c < 4; ++c) {
        #pragma unroll
        for (int k = 0; k < 4; ++k) W[c][k] = conv_w[c * 4 + k];
        Bc[c] = conv_b[c];
    }
    const float qp0 = q_params[0], qp1 = q_params[1];
    const float qp2 = q_params[2], qp3 = q_params[3];
    const float q4  = q_params[4];
    const float cq4 = __cosf(q4), sq4 = __sinf(q4);

    // ---- Step 1: conv (2x2, stride 2, 4 ch) -> flat region comb[s][0..783]
    // fp32 math, fp16 store (pairs, r even -> 4B aligned).
    for (int p = tid; p < SPB * 14 * 7; p += THREADS) {
        const int s = p / 98, t = p % 98;
        const int h = t / 7, wp = t % 7;
        const float* xp = x + (size_t)(n0 + s) * 784 + 56 * h + 4 * wp;
        const float4 r0 = *reinterpret_cast<const float4*>(xp);
        const float4 r1 = *reinterpret_cast<const float4*>(xp + 28);
        const int r = h * 14 + 2 * wp;
        #pragma unroll
        for (int c = 0; c < 4; ++c) {
            const float v0 =
                fmaf(r0.x, W[c][0], fmaf(r0.y, W[c][1],
                fmaf(r1.x, W[c][2], fmaf(r1.y, W[c][3], Bc[c]))));
            const float v1 =
                fmaf(r0.z, W[c][0], fmaf(r0.w, W[c][1],
                fmaf(r1.z, W[c][2], fmaf(r1.w, W[c][3], Bc[c]))));
            *reinterpret_cast<__half2*>(&comb[s][c * 196 + r]) =
                __floats2half2_rn(v0, v1);
        }
    }
    __syncthreads();

    // ---- Step 2: quantum features on 2x2 patches of the 28x28 view of flat
    for (int p = tid; p < SPB * 196; p += THREADS) {
        const int s = p / 196, r = p % 196;
        const int i = r / 14, j = r % 14;
        const int base = 56 * i + 2 * j;   // even -> 4B aligned
        const float2 d01 = __half22float2(
            *reinterpret_cast<const __half2*>(&comb[s][base]));
        const float2 d23 = __half22float2(
            *reinterpret_cast<const __half2*>(&comb[s][base + 28]));
        const float a0 = d01.x + qp0, a1 = d01.y + qp1;
        const float a2 = d23.x + qp2, a3 = d23.y + qp3;
        const float c0 = __cosf(a0);
        const float c1 = __cosf(a1), s1 = __sinf(a1);
        const float c2 = __cosf(a2), c3 = __cosf(a3);
        const float z0 = c0;
        const float z1 = cq4 * c0 * c1 - sq4 * s1;
        const float z2 = z1 * c2;
        const float z3 = c2 * c3;
        union { uint2 u; __half2 h[2]; } O;
        O.h[0] = __floats2half2_rn(z0, z1);
        O.h[1] = __floats2half2_rn(z2, z3);
        *reinterpret_cast<uint2*>(&comb[s][784 + r * 4]) = O.u;  // 8B aligned
    }
    __syncthreads();

    // ---- Step 3: linear [1568]x[10] + log_softmax.
    // Wave w = (pair pr, class-group cg): samples {2pr, 2pr+1},
    // classes [5cg, 5cg+5), FULL K. 10 accumulators per thread.
    const int wave = tid >> 6, lane = tid & 63;
    const int pr = wave & 1;
    const int cg = wave >> 1;
    const int s0 = 2 * pr, s1 = s0 + 1;
    const int cbase = 5 * cg;

    float acc0[5], acc1[5];
    #pragma unroll
    for (int ci = 0; ci < 5; ++ci) { acc0[ci] = 0.f; acc1[ci] = 0.f; }

    // 6 full strips of 256 floats: covers [0, 1536)
    #pragma unroll
    for (int kb = 0; kb < 6; ++kb) {
        const int k = kb * 256 + lane * 4;   // 8B-aligned fp16 quad
        union { uint2 u; __half2 hh[2]; } U0, U1;
        U0.u = *reinterpret_cast<const uint2*>(&comb[s0][k]);
        U1.u = *reinterpret_cast<const uint2*>(&comb[s1][k]);
        const float2 a0 = __half22float2(U0.hh[0]);
        const float2 b0 = __half22float2(U0.hh[1]);
        const float2 a1 = __half22float2(U1.hh[0]);
        const float2 b1 = __half22float2(U1.hh[1]);
        #pragma unroll
        for (int ci = 0; ci < 5; ++ci) {
            const float4 w4 =
                *reinterpret_cast<const float4*>(&lin_w[(cbase + ci) * FEAT + k]);
            acc0[ci] = fmaf(a0.x, w4.x, fmaf(a0.y, w4.y,
                       fmaf(b0.x, w4.z, fmaf(b0.y, w4.w, acc0[ci]))));
            acc1[ci] = fmaf(a1.x, w4.x, fmaf(a1.y, w4.y,
                       fmaf(b1.x, w4.z, fmaf(b1.y, w4.w, acc1[ci]))));
        }
    }
    // tail [1536,1568): 32 scalars, lanes 0..31
    if (lane < 32) {
        const int k = 1536 + lane;
        const float v0 = __half2float(comb[s0][k]);
        const float v1 = __half2float(comb[s1][k]);
        #pragma unroll
        for (int ci = 0; ci < 5; ++ci) {
            const float w = lin_w[(cbase + ci) * FEAT + k];
            acc0[ci] = fmaf(v0, w, acc0[ci]);
            acc1[ci] = fmaf(v1, w, acc1[ci]);
        }
    }

    // ---- Packed reduction: 10 partials -> 5 per lane -> butterfly.
    // Stage 1 (xor 1): even lanes keep sample s0, odd keep s1.
    float w5[5];
    {
        const bool hi = (lane & 1) != 0;
        #pragma unroll
        for (int i = 0; i < 5; ++i) {
            const float t = hi ? acc0[i] : acc1[i];        // given-away half
            const float r = __shfl_xor(t, 1, 64);
            w5[i] = (hi ? acc1[i] : acc0[i]) + r;
        }
    }
    // Stages 2-6: plain butterfly on 5 values (xor 2,4,8,16,32).
    #pragma unroll
    for (int m = 2; m < 64; m <<= 1) {
        #pragma unroll
        for (int i = 0; i < 5; ++i)
            w5[i] += __shfl_xor(w5[i], m, 64);
    }
    // lane0: s0 sums, lane1: s1 sums (classes cbase..cbase+4), full 64-lane.
    if (lane < 2) {
        const int ss = lane ? s1 : s0;
        #pragma unroll
        for (int i = 0; i < 5; ++i)
            part[ss][cg][i] = w5[i];
    }
    __syncthreads();

    // ---- Epilogue: one thread per sample, combine class-groups + log_softmax
    if (tid < SPB) {
        const int s = tid;
        float lg[NCLS], mx = -1e30f;
        #pragma unroll
        for (int c = 0; c < NCLS; ++c) {
            lg[c] = part[s][c / 5][c % 5] + lin_b[c];
            mx = fmaxf(mx, lg[c]);
        }
        float sum = 0.f;
        #pragma unroll
        for (int c = 0; c < NCLS; ++c) sum += __expf(lg[c] - mx);
        const float lse = mx + __logf(sum);
        float* o = out + (size_t)(n0 + s) * NCLS;
        #pragma unroll
        for (int c = 0; c < NCLS; ++c) o[c] = lg[c] - lse;
    }
}

extern "C" void kernel_launch(void* const* d_in, const int* in_sizes, int n_in,
                              void* d_out, int out_size, void* d_ws, size_t ws_size,
                              hipStream_t stream) {
    const float* x        = (const float*)d_in[0];
    const float* conv_w   = (const float*)d_in[1];
    const float* conv_b   = (const float*)d_in[2];
    const float* q_params = (const float*)d_in[3];
    const float* lin_w    = (const float*)d_in[4];
    const float* lin_b    = (const float*)d_in[5];
    float* out = (float*)d_out;

    const int B = in_sizes[0] / 784;   // 8192
    const int nblocks = B / SPB;       // 2048

    quanv_fused_kernel<<<nblocks, THREADS, 0, stream>>>(
        x, conv_w, conv_b, q_params, lin_w, lin_b, out);
}

// Round 15
// 93.026 us; speedup vs baseline: 1.6484x; 1.0050x over previous
//
#include <hip/hip_runtime.h>
#include <hip/hip_bf16.h>
#include <hip/hip_fp16.h>

// Fully fused QuanvolutionHybridClassifier forward (round 15).
//
// Circuit collapse (verified): with a_w = d_w + q_w,
//   z0 = cos a0
//   z1 = cos q4 * cos a0 * cos a1 - sin q4 * sin a1
//   z2 = z1 * cos a2
//   z3 = cos a2 * cos a3
//
// Round-15: r10/r13/r14 (three step-3 organizations, 6-8 blk/CU) all tie
// at ~93.6us => scalar step 3 is issue/latency-bound, occupancy is not
// the lever. Pivot: step 3 via MFMA. Per block [4 x 1568]x[1568 x 10],
// K = 49*32 exactly. Wave w owns K-chunks {w, w+4, ...} (13/12/12/12),
// one mfma_f32_16x16x32_f16 per chunk into a single f32x4 acc.
// A = comb fp16 LDS rows (m=lane&15, clamp>=4 -> sample 0, broadcast);
// B = lin_w rows cvt fp32->fp16 in flight (n=lane&15, clamp>=10 -> 9;
// junk lands in discarded C rows/cols, loads stay in-bounds).
// D layout (m89-verified): col=lane&15, row=(lane>>4)*4+i -> lanes 0-15
// hold sample-rows 0-3; 1KB partC + 4-thread softmax epilogue.
// Replaces ~430 scalar instr/thread (240 FMA + 30 loads + 30 shuffles)
// with ~13*(ds_read_b128 + 2 dwordx4 + 8 cvt + 1 MFMA) per wave.
// Steps 1-2 byte-identical to r14 (fp16 comb staging) for attribution.

#define SPB 4          // samples per block
#define THREADS 256
#define NCLS 10
#define FEAT 1568      // 784 flat + 784 quantum

typedef _Float16 half8 __attribute__((ext_vector_type(8)));
typedef float f32x4 __attribute__((ext_vector_type(4)));

__global__ __launch_bounds__(THREADS, 8)
void quanv_fused_kernel(const float* __restrict__ x,        // [B,1,28,28]
                        const float* __restrict__ conv_w,   // [4,1,2,2]
                        const float* __restrict__ conv_b,   // [4]
                        const float* __restrict__ q_params, // [5]
                        const float* __restrict__ lin_w,    // [10,1568]
                        const float* __restrict__ lin_b,    // [10]
                        float* __restrict__ out)            // [B,10]
{
    __shared__ __attribute__((aligned(16))) __half comb[SPB][FEAT]; // 12544 B
    __shared__ float partC[4][4][16];    // [wave][sample-row][class-col] 1KB

    const int tid = threadIdx.x;
    const int n0  = blockIdx.x * SPB;

    // ---- uniform small params (L1-broadcast loads) ----
    float W[4][4], Bc[4];
    #pragma unroll
    for (int c = 0; c < 4; ++c) {
        #pragma unroll
        for (int k = 0; k < 4; ++k) W[c][k] = conv_w[c * 4 + k];
        Bc[c] = conv_b[c];
    }
    const float qp0 = q_params[0], qp1 = q_params[1];
    const float qp2 = q_params[2], qp3 = q_params[3];
    const float q4  = q_params[4];
    const float cq4 = __cosf(q4), sq4 = __sinf(q4);

    // ---- Step 1: conv (2x2, stride 2, 4 ch) -> flat region comb[s][0..783]
    // fp32 math, fp16 store (pairs, r even -> 4B aligned).
    for (int p = tid; p < SPB * 14 * 7; p += THREADS) {
        const int s = p / 98, t = p % 98;
        const int h = t / 7, wp = t % 7;
        const float* xp = x + (size_t)(n0 + s) * 784 + 56 * h + 4 * wp;
        const float4 r0 = *reinterpret_cast<const float4*>(xp);
        const float4 r1 = *reinterpret_cast<const float4*>(xp + 28);
        const int r = h * 14 + 2 * wp;
        #pragma unroll
        for (int c = 0; c < 4; ++c) {
            const float v0 =
                fmaf(r0.x, W[c][0], fmaf(r0.y, W[c][1],
                fmaf(r1.x, W[c][2], fmaf(r1.y, W[c][3], Bc[c]))));
            const float v1 =
                fmaf(r0.z, W[c][0], fmaf(r0.w, W[c][1],
                fmaf(r1.z, W[c][2], fmaf(r1.w, W[c][3], Bc[c]))));
            *reinterpret_cast<__half2*>(&comb[s][c * 196 + r]) =
                __floats2half2_rn(v0, v1);
        }
    }
    __syncthreads();

    // ---- Step 2: quantum features on 2x2 patches of the 28x28 view of flat
    for (int p = tid; p < SPB * 196; p += THREADS) {
        const int s = p / 196, r = p % 196;
        const int i = r / 14, j = r % 14;
        const int base = 56 * i + 2 * j;   // even -> 4B aligned
        const float2 d01 = __half22float2(
            *reinterpret_cast<const __half2*>(&comb[s][base]));
        const float2 d23 = __half22float2(
            *reinterpret_cast<const __half2*>(&comb[s][base + 28]));
        const float a0 = d01.x + qp0, a1 = d01.y + qp1;
        const float a2 = d23.x + qp2, a3 = d23.y + qp3;
        const float c0 = __cosf(a0);
        const float c1 = __cosf(a1), s1 = __sinf(a1);
        const float c2 = __cosf(a2), c3 = __cosf(a3);
        const float z0 = c0;
        const float z1 = cq4 * c0 * c1 - sq4 * s1;
        const float z2 = z1 * c2;
        const float z3 = c2 * c3;
        union { uint2 u; __half2 h[2]; } O;
        O.h[0] = __floats2half2_rn(z0, z1);
        O.h[1] = __floats2half2_rn(z2, z3);
        *reinterpret_cast<uint2*>(&comb[s][784 + r * 4]) = O.u;  // 8B aligned
    }
    __syncthreads();

    // ---- Step 3: MFMA GEMM [4 x 1568] x [1568 x 10] + log_softmax.
    // Wave w: K-chunks kc = w, w+4, ... < 49 (32 k-elems each, no tail).
    const int wave = tid >> 6, lane = tid & 63;
    const int l15  = lane & 15;
    const int srow = (l15 < SPB)  ? l15 : 0;          // A row (sample), clamp
    const int wrow = (l15 < NCLS) ? l15 : (NCLS - 1); // B col (class),  clamp
    const int ksub = (lane >> 4) * 8;

    f32x4 acc = {0.f, 0.f, 0.f, 0.f};
    for (int kc = wave; kc < 49; kc += 4) {
        const int k0 = kc * 32 + ksub;
        const half8 a = *reinterpret_cast<const half8*>(&comb[srow][k0]);
        const float4 w0 =
            *reinterpret_cast<const float4*>(&lin_w[wrow * FEAT + k0]);
        const float4 w1 =
            *reinterpret_cast<const float4*>(&lin_w[wrow * FEAT + k0 + 4]);
        half8 b;
        b[0] = (_Float16)w0.x; b[1] = (_Float16)w0.y;
        b[2] = (_Float16)w0.z; b[3] = (_Float16)w0.w;
        b[4] = (_Float16)w1.x; b[5] = (_Float16)w1.y;
        b[6] = (_Float16)w1.z; b[7] = (_Float16)w1.w;
        acc = __builtin_amdgcn_mfma_f32_16x16x32_f16(a, b, acc, 0, 0, 0);
    }

    // D layout: col = lane&15, row = (lane>>4)*4 + i. Lanes 0-15 hold
    // rows 0-3 (= samples); cols >= NCLS are junk and never read.
    if (lane < 16) {
        #pragma unroll
        for (int i = 0; i < 4; ++i)
            partC[wave][i][lane] = acc[i];
    }
    __syncthreads();

    // ---- Epilogue: one thread per sample combines 4 wave-partials + softmax
    if (tid < SPB) {
        const int s = tid;
        float lg[NCLS], mx = -1e30f;
        #pragma unroll
        for (int c = 0; c < NCLS; ++c) {
            lg[c] = partC[0][s][c] + partC[1][s][c] +
                    partC[2][s][c] + partC[3][s][c] + lin_b[c];
            mx = fmaxf(mx, lg[c]);
        }
        float sum = 0.f;
        #pragma unroll
        for (int c = 0; c < NCLS; ++c) sum += __expf(lg[c] - mx);
        const float lse = mx + __logf(sum);
        float* o = out + (size_t)(n0 + s) * NCLS;
        #pragma unroll
        for (int c = 0; c < NCLS; ++c) o[c] = lg[c] - lse;
    }
}

extern "C" void kernel_launch(void* const* d_in, const int* in_sizes, int n_in,
                              void* d_out, int out_size, void* d_ws, size_t ws_size,
                              hipStream_t stream) {
    const float* x        = (const float*)d_in[0];
    const float* conv_w   = (const float*)d_in[1];
    const float* conv_b   = (const float*)d_in[2];
    const float* q_params = (const float*)d_in[3];
    const float* lin_w    = (const float*)d_in[4];
    const float* lin_b    = (const float*)d_in[5];
    float* out = (float*)d_out;

    const int B = in_sizes[0] / 784;   // 8192
    const int nblocks = B / SPB;       // 2048

    quanv_fused_kernel<<<nblocks, THREADS, 0, stream>>>(
        x, conv_w, conv_b, q_params, lin_w, lin_b, out);
}

// Round 17
// 87.501 us; speedup vs baseline: 1.7525x; 1.0631x over previous
//
#include <hip/hip_runtime.h>
#include <hip/hip_bf16.h>
#include <hip/hip_fp16.h>

// Fully fused QuanvolutionHybridClassifier forward (round 16 design,
// resubmitted — round-16 bench failed on GPU acquisition, no counters).
//
// Circuit collapse (verified): with a_w = d_w + q_w,
//   z0 = cos a0
//   z1 = cos q4 * cos a0 * cos a1 - sin q4 * sin a1
//   z2 = z1 * cos a2
//   z3 = cos a2 * cos a3
//
// Round-16: r10/r14/r15 (scalar fp32, scalar fp16, MFMA step-3) all tie
// at 93.3 +/- 0.4 us => step 3 is off the critical path; kernel time is
// per-block fixed cost (staging, 2 barriers, dispatch) + per-byte cost.
// ONE change vs r15: SPB 4 -> 8 (grid 1024). The 16x16 MFMA C-tile holds
// 8 real sample rows (rows 8-15 clamp to row 0, discarded); per-sample
// fixed cost and lin_w traffic halve; steps 1-2 get 2x ILP/thread.
// LDS 25.1+2 KB -> 4 blocks/CU (launch_bounds(256,4), 128-VGPR cap, no
// r12-style spill); grid 1024 = exactly co-resident.

#define SPB 8          // samples per block
#define THREADS 256
#define NCLS 10
#define FEAT 1568      // 784 flat + 784 quantum

typedef _Float16 half8 __attribute__((ext_vector_type(8)));
typedef float f32x4 __attribute__((ext_vector_type(4)));

__global__ __launch_bounds__(THREADS, 4)
void quanv_fused_kernel(const float* __restrict__ x,        // [B,1,28,28]
                        const float* __restrict__ conv_w,   // [4,1,2,2]
                        const float* __restrict__ conv_b,   // [4]
                        const float* __restrict__ q_params, // [5]
                        const float* __restrict__ lin_w,    // [10,1568]
                        const float* __restrict__ lin_b,    // [10]
                        float* __restrict__ out)            // [B,10]
{
    __shared__ __attribute__((aligned(16))) __half comb[SPB][FEAT]; // 25088 B
    __shared__ float partC[4][SPB][16];  // [wave][sample-row][class-col] 2KB

    const int tid = threadIdx.x;
    const int n0  = blockIdx.x * SPB;

    // ---- uniform small params (L1-broadcast loads) ----
    float W[4][4], Bc[4];
    #pragma unroll
    for (int c = 0; c < 4; ++c) {
        #pragma unroll
        for (int k = 0; k < 4; ++k) W[c][k] = conv_w[c * 4 + k];
        Bc[c] = conv_b[c];
    }
    const float qp0 = q_params[0], qp1 = q_params[1];
    const float qp2 = q_params[2], qp3 = q_params[3];
    const float q4  = q_params[4];
    const float cq4 = __cosf(q4), sq4 = __sinf(q4);

    // ---- Step 1: conv (2x2, stride 2, 4 ch) -> flat region comb[s][0..783]
    // fp32 math, fp16 store (pairs, r even -> 4B aligned).
    for (int p = tid; p < SPB * 98; p += THREADS) {
        const int s = p / 98, t = p % 98;
        const int h = t / 7, wp = t % 7;
        const float* xp = x + (size_t)(n0 + s) * 784 + 56 * h + 4 * wp;
        const float4 r0 = *reinterpret_cast<const float4*>(xp);
        const float4 r1 = *reinterpret_cast<const float4*>(xp + 28);
        const int r = h * 14 + 2 * wp;
        #pragma unroll
        for (int c = 0; c < 4; ++c) {
            const float v0 =
                fmaf(r0.x, W[c][0], fmaf(r0.y, W[c][1],
                fmaf(r1.x, W[c][2], fmaf(r1.y, W[c][3], Bc[c]))));
            const float v1 =
                fmaf(r0.z, W[c][0], fmaf(r0.w, W[c][1],
                fmaf(r1.z, W[c][2], fmaf(r1.w, W[c][3], Bc[c]))));
            *reinterpret_cast<__half2*>(&comb[s][c * 196 + r]) =
                __floats2half2_rn(v0, v1);
        }
    }
    __syncthreads();

    // ---- Step 2: quantum features on 2x2 patches of the 28x28 view of flat
    for (int p = tid; p < SPB * 196; p += THREADS) {
        const int s = p / 196, r = p % 196;
        const int i = r / 14, j = r % 14;
        const int base = 56 * i + 2 * j;   // even -> 4B aligned
        const float2 d01 = __half22float2(
            *reinterpret_cast<const __half2*>(&comb[s][base]));
        const float2 d23 = __half22float2(
            *reinterpret_cast<const __half2*>(&comb[s][base + 28]));
        const float a0 = d01.x + qp0, a1 = d01.y + qp1;
        const float a2 = d23.x + qp2, a3 = d23.y + qp3;
        const float c0 = __cosf(a0);
        const float c1 = __cosf(a1), s1 = __sinf(a1);
        const float c2 = __cosf(a2), c3 = __cosf(a3);
        const float z0 = c0;
        const float z1 = cq4 * c0 * c1 - sq4 * s1;
        const float z2 = z1 * c2;
        const float z3 = c2 * c3;
        union { uint2 u; __half2 h[2]; } O;
        O.h[0] = __floats2half2_rn(z0, z1);
        O.h[1] = __floats2half2_rn(z2, z3);
        *reinterpret_cast<uint2*>(&comb[s][784 + r * 4]) = O.u;  // 8B aligned
    }
    __syncthreads();

    // ---- Step 3: MFMA GEMM [8 x 1568] x [1568 x 10] + log_softmax.
    // Wave w: K-chunks kc = w, w+4, ... < 49 (32 k-elems each, no tail).
    const int wave = tid >> 6, lane = tid & 63;
    const int l15  = lane & 15;
    const int srow = (l15 < SPB)  ? l15 : 0;          // A row (sample), clamp
    const int wrow = (l15 < NCLS) ? l15 : (NCLS - 1); // B col (class),  clamp
    const int ksub = (lane >> 4) * 8;

    f32x4 acc = {0.f, 0.f, 0.f, 0.f};
    for (int kc = wave; kc < 49; kc += 4) {
        const int k0 = kc * 32 + ksub;
        const half8 a = *reinterpret_cast<const half8*>(&comb[srow][k0]);
        const float4 w0 =
            *reinterpret_cast<const float4*>(&lin_w[wrow * FEAT + k0]);
        const float4 w1 =
            *reinterpret_cast<const float4*>(&lin_w[wrow * FEAT + k0 + 4]);
        half8 b;
        b[0] = (_Float16)w0.x; b[1] = (_Float16)w0.y;
        b[2] = (_Float16)w0.z; b[3] = (_Float16)w0.w;
        b[4] = (_Float16)w1.x; b[5] = (_Float16)w1.y;
        b[6] = (_Float16)w1.z; b[7] = (_Float16)w1.w;
        acc = __builtin_amdgcn_mfma_f32_16x16x32_f16(a, b, acc, 0, 0, 0);
    }

    // D layout (m89-verified): col = lane&15, row = (lane>>4)*4 + i.
    // Lanes 0-31 hold rows 0-7 (= samples 0-7); cols >= NCLS are junk.
    if (lane < 32) {
        const int rbase = (lane >> 4) * 4;
        #pragma unroll
        for (int i = 0; i < 4; ++i)
            partC[wave][rbase + i][l15] = acc[i];
    }
    __syncthreads();

    // ---- Epilogue: one thread per sample combines 4 wave-partials + softmax
    if (tid < SPB) {
        const int s = tid;
        float lg[NCLS], mx = -1e30f;
        #pragma unroll
        for (int c = 0; c < NCLS; ++c) {
            lg[c] = partC[0][s][c] + partC[1][s][c] +
                    partC[2][s][c] + partC[3][s][c] + lin_b[c];
            mx = fmaxf(mx, lg[c]);
        }
        float sum = 0.f;
        #pragma unroll
        for (int c = 0; c < NCLS; ++c) sum += __expf(lg[c] - mx);
        const float lse = mx + __logf(sum);
        float* o = out + (size_t)(n0 + s) * NCLS;
        #pragma unroll
        for (int c = 0; c < NCLS; ++c) o[c] = lg[c] - lse;
    }
}

extern "C" void kernel_launch(void* const* d_in, const int* in_sizes, int n_in,
                              void* d_out, int out_size, void* d_ws, size_t ws_size,
                              hipStream_t stream) {
    const float* x        = (const float*)d_in[0];
    const float* conv_w   = (const float*)d_in[1];
    const float* conv_b   = (const float*)d_in[2];
    const float* q_params = (const float*)d_in[3];
    const float* lin_w    = (const float*)d_in[4];
    const float* lin_b    = (const float*)d_in[5];
    float* out = (float*)d_out;

    const int B = in_sizes[0] / 784;   // 8192
    const int nblocks = B / SPB;       // 1024

    quanv_fused_kernel<<<nblocks, THREADS, 0, stream>>>(
        x, conv_w, conv_b, q_params, lin_w, lin_b, out);
}